// Round 12
// baseline (145.296 us; speedup 1.0000x reference)
//
#include <hip/hip_runtime.h>

#define N_NODES   100000
#define N_EDGES   600000
#define D_FEAT    128
#define N_CLASSES 40
#define USTRIDE   64                // bf16 elems/row -> 128 B, one cache line

#define NPAD      100352            // N_NODES padded to 1024 multiple
#define SCAN_NBLK (NPAD / 1024)     // 98

// ---------- bf16 helpers (RTNE) ----------
__device__ __forceinline__ float bf2f(unsigned int h) { return __uint_as_float(h << 16); }
__device__ __forceinline__ float bf2f_lo(unsigned int u) { return __uint_as_float(u << 16); }
__device__ __forceinline__ float bf2f_hi(unsigned int u) { return __uint_as_float(u & 0xFFFF0000u); }
__device__ __forceinline__ unsigned int f2bf(float f) {
    unsigned int u = __float_as_uint(f);
    return (u + 0x7FFFu + ((u >> 16) & 1u)) >> 16;
}
__device__ __forceinline__ float4 up4(uint2 v) {
    return make_float4(bf2f(v.x & 0xFFFFu), bf2f(v.x >> 16),
                       bf2f(v.y & 0xFFFFu), bf2f(v.y >> 16));
}
__device__ __forceinline__ uint2 pk4(float4 f) {
    uint2 r;
    r.x = f2bf(f.x) | (f2bf(f.y) << 16);
    r.y = f2bf(f.z) | (f2bf(f.w) << 16);
    return r;
}

// ================= CSR build =================

__global__ void k_zero(int4* __restrict__ deg4) {
    int i = blockIdx.x * blockDim.x + threadIdx.x;
    if (i < NPAD / 4) deg4[i] = make_int4(0, 0, 0, 0);
}

__global__ void k_count(const int* __restrict__ edst, int* __restrict__ deg) {
    int e = blockIdx.x * blockDim.x + threadIdx.x;
    if (e < N_EDGES) atomicAdd(&deg[edst[e]], 1);
}

__global__ __launch_bounds__(256) void k_scan1(const int* __restrict__ deg,
                                               int* __restrict__ row_ptr,
                                               int* __restrict__ blksum) {
    __shared__ int wsum[4];
    int t = threadIdx.x;
    int lane = t & 63, w = t >> 6;
    int base = blockIdx.x * 1024 + t * 4;
    int4 v = *(const int4*)(deg + base);
    int s0 = v.x, s1 = s0 + v.y, s2 = s1 + v.z, s3 = s2 + v.w;
    int inc = s3;
#pragma unroll
    for (int d = 1; d < 64; d <<= 1) {
        int y = __shfl_up(inc, d, 64);
        if (lane >= d) inc += y;
    }
    if (lane == 63) wsum[w] = inc;
    __syncthreads();
    int woff = 0;
#pragma unroll
    for (int j = 0; j < 3; ++j) woff += (j < w) ? wsum[j] : 0;
    int texcl = woff + inc - s3;
    int4 o;
    o.x = texcl; o.y = texcl + s0; o.z = texcl + s1; o.w = texcl + s2;
    *(int4*)(row_ptr + base) = o;
    if (t == 255) blksum[blockIdx.x] = woff + inc;
}

__global__ __launch_bounds__(256) void k_scan2(const int* __restrict__ deg,
                                               int* __restrict__ row_ptr,
                                               int* __restrict__ cursor,
                                               float* __restrict__ dinv,
                                               const int* __restrict__ blksum) {
    __shared__ int s[SCAN_NBLK];
    int t = threadIdx.x;
    int blk = blockIdx.x;
    if (t < SCAN_NBLK) s[t] = blksum[t];
    __syncthreads();
    int off = 0;
    for (int j = 0; j < blk; ++j) off += s[j];
    int base = blk * 1024 + t * 4;
    int4 v = *(int4*)(row_ptr + base);
    v.x += off; v.y += off; v.z += off; v.w += off;
    *(int4*)(row_ptr + base) = v;
    *(int4*)(cursor + base) = v;
    int4 d = *(const int4*)(deg + base);
    float4 di;
    di.x = rsqrtf((float)(d.x + 1));
    di.y = rsqrtf((float)(d.y + 1));
    di.z = rsqrtf((float)(d.z + 1));
    di.w = rsqrtf((float)(d.w + 1));
    *(float4*)(dinv + base) = di;
}

__global__ void k_fill(const int* __restrict__ esrc, const int* __restrict__ edst,
                       int* __restrict__ cursor, int* __restrict__ csr_src) {
    int e = blockIdx.x * blockDim.x + threadIdx.x;
    if (e < N_EDGES) {
        int d = edst[e];
        int pos = atomicAdd(&cursor[d], 1);
        csr_src[pos] = esrc[e];
    }
}

// ================= u0 = bf16( (x @ W^T) * dinv[node] ) =================
// 1 node/quad (4 thr x 10 classes), 6250 waves. W staged in LDS as BF16
// pairs: one ds_read_b128 covers 8 W elems -> LDS traffic 2.0 GB -> 1.0 GB
// and LDS instr count halves (the ~30us LDS-bandwidth floor was the
// invariant pinning every fp32-LDS variant at ~40us). Unpack = 1 VALU
// op/elem (<<16 or &0xFFFF0000). Row stride 68 uints -> the 4 sub-group
// addresses land on banks {b,b+8,b+16,b+24}: conflict-free.

#define WSTRIDE 68   // uints per W row (64 data + 4 pad)

__global__ __launch_bounds__(256) void k_gemm(const float* __restrict__ x,
                                              const float* __restrict__ W,
                                              const float* __restrict__ dinv,
                                              unsigned short* __restrict__ y) {
    __shared__ unsigned int Wl[N_CLASSES][WSTRIDE];   // 10.6 KB
    int t = threadIdx.x;

    // stage + convert W (40 rows x 64 bf16-pairs)
    for (int f = t; f < N_CLASSES * (D_FEAT / 2); f += 256) {
        int c = f >> 6, p = f & 63;
        float2 w = ((const float2*)W)[f];
        Wl[c][p] = f2bf(w.x) | (f2bf(w.y) << 16);
    }
    __syncthreads();

    int quad = t >> 2;                    // 0..63
    int sub  = t & 3;
    int c0   = sub * 10;
    int node = blockIdx.x * 64 + quad;
    if (node >= N_NODES) return;

    const float4* xp = (const float4*)(x + (size_t)node * D_FEAT);

    float acc[10];
#pragma unroll
    for (int j = 0; j < 10; ++j) acc[j] = 0.f;

    for (int d4 = 0; d4 < D_FEAT / 4; d4 += 2) {
        float4 x0 = xp[d4];
        float4 x1 = xp[d4 + 1];
#pragma unroll
        for (int j = 0; j < 10; ++j) {
            uint4 wv = *(const uint4*)&Wl[c0 + j][d4 * 2];   // 8 bf16 W elems
            acc[j] += x0.x * bf2f_lo(wv.x) + x0.y * bf2f_hi(wv.x)
                    + x0.z * bf2f_lo(wv.y) + x0.w * bf2f_hi(wv.y)
                    + x1.x * bf2f_lo(wv.z) + x1.y * bf2f_hi(wv.z)
                    + x1.z * bf2f_lo(wv.w) + x1.w * bf2f_hi(wv.w);
        }
    }

    float di = dinv[node];
    unsigned int* up = (unsigned int*)y;
#pragma unroll
    for (int p = 0; p < 5; ++p) {
        unsigned int w = f2bf(acc[2 * p] * di) | (f2bf(acc[2 * p + 1] * di) << 16);
        up[(size_t)node * (USTRIDE / 2) + sub * 5 + p] = w;
    }
}

// ================= CSR gather on bf16 u (8 threads/node) =================
// u_out[d] = dinv[d]^2 * ( u_in[d] + sum u_in[s] ); rows are ONE 128B line.
// sub = class half (bit0, 5 uint2 = 40B), par = edge phase mod 4 (bits1-2).

__global__ __launch_bounds__(256) void k_gather(const unsigned short* __restrict__ yin,
                                                unsigned short* __restrict__ yout,
                                                const float* __restrict__ dinv,
                                                const int* __restrict__ row_ptr,
                                                const int* __restrict__ csr_src) {
    int t = blockIdx.x * blockDim.x + threadIdx.x;
    int i = t >> 3;
    if (i >= N_NODES) return;
    int sub = t & 1;
    int par = (t >> 1) & 3;
    const uint2* yb = (const uint2*)yin;

    float4 a[5];
    if (par == 0) {
        const uint2* self = yb + (size_t)i * 16 + sub * 5;
#pragma unroll
        for (int r = 0; r < 5; ++r) a[r] = up4(self[r]);
    } else {
#pragma unroll
        for (int r = 0; r < 5; ++r) a[r] = make_float4(0.f, 0.f, 0.f, 0.f);
    }

    int e = row_ptr[i] + par, end = row_ptr[i + 1];
    for (; e < end; e += 4) {
        int s = csr_src[e];
        const uint2* p = yb + (size_t)s * 16 + sub * 5;
        uint2 w[5];
#pragma unroll
        for (int r = 0; r < 5; ++r) w[r] = p[r];
#pragma unroll
        for (int r = 0; r < 5; ++r) {
            float4 v = up4(w[r]);
            a[r].x += v.x; a[r].y += v.y; a[r].z += v.z; a[r].w += v.w;
        }
    }

#pragma unroll
    for (int d = 2; d <= 4; d <<= 1) {
#pragma unroll
        for (int r = 0; r < 5; ++r) {
            a[r].x += __shfl_xor(a[r].x, d); a[r].y += __shfl_xor(a[r].y, d);
            a[r].z += __shfl_xor(a[r].z, d); a[r].w += __shfl_xor(a[r].w, d);
        }
    }

    if (par == 0) {
        float di = dinv[i];
        float s2 = di * di;
        uint2* o = (uint2*)yout + (size_t)i * 16 + sub * 5;
#pragma unroll
        for (int r = 0; r < 5; ++r) {
            o[r] = pk4(make_float4(a[r].x * s2, a[r].y * s2, a[r].z * s2, a[r].w * s2));
        }
    }
}

// final round: logits = dinv*v + b, log_softmax, fp32 out
__global__ __launch_bounds__(256) void k_gather_out(const unsigned short* __restrict__ yin,
                                                    float* __restrict__ out,
                                                    const float* __restrict__ dinv,
                                                    const int* __restrict__ row_ptr,
                                                    const int* __restrict__ csr_src,
                                                    const float* __restrict__ bias) {
    int t = blockIdx.x * blockDim.x + threadIdx.x;
    int i = t >> 3;
    if (i >= N_NODES) return;
    int sub = t & 1;
    int par = (t >> 1) & 3;
    const uint2* yb = (const uint2*)yin;

    float4 a[5];
    if (par == 0) {
        const uint2* self = yb + (size_t)i * 16 + sub * 5;
#pragma unroll
        for (int r = 0; r < 5; ++r) a[r] = up4(self[r]);
    } else {
#pragma unroll
        for (int r = 0; r < 5; ++r) a[r] = make_float4(0.f, 0.f, 0.f, 0.f);
    }

    int e = row_ptr[i] + par, end = row_ptr[i + 1];
    for (; e < end; e += 4) {
        int s = csr_src[e];
        const uint2* p = yb + (size_t)s * 16 + sub * 5;
        uint2 w[5];
#pragma unroll
        for (int r = 0; r < 5; ++r) w[r] = p[r];
#pragma unroll
        for (int r = 0; r < 5; ++r) {
            float4 v = up4(w[r]);
            a[r].x += v.x; a[r].y += v.y; a[r].z += v.z; a[r].w += v.w;
        }
    }

#pragma unroll
    for (int d = 2; d <= 4; d <<= 1) {
#pragma unroll
        for (int r = 0; r < 5; ++r) {
            a[r].x += __shfl_xor(a[r].x, d); a[r].y += __shfl_xor(a[r].y, d);
            a[r].z += __shfl_xor(a[r].z, d); a[r].w += __shfl_xor(a[r].w, d);
        }
    }

    float di = dinv[i];
    const float4* b4 = (const float4*)bias + sub * 5;
    float4 l[5];
    float m = -INFINITY;
#pragma unroll
    for (int r = 0; r < 5; ++r) {
        float4 b = b4[r];
        l[r].x = a[r].x * di + b.x;
        l[r].y = a[r].y * di + b.y;
        l[r].z = a[r].z * di + b.z;
        l[r].w = a[r].w * di + b.w;
        m = fmaxf(m, fmaxf(fmaxf(l[r].x, l[r].y), fmaxf(l[r].z, l[r].w)));
    }
    m = fmaxf(m, __shfl_xor(m, 1));     // combine class halves (bit 0)
    float s = 0.f;
#pragma unroll
    for (int r = 0; r < 5; ++r) {
        s += __expf(l[r].x - m) + __expf(l[r].y - m)
           + __expf(l[r].z - m) + __expf(l[r].w - m);
    }
    s += __shfl_xor(s, 1);
    float lse = __logf(s) + m;

    if (par == 0) {
        float4* o = (float4*)out + (size_t)i * 10 + sub * 5;
#pragma unroll
        for (int r = 0; r < 5; ++r) {
            o[r] = make_float4(l[r].x - lse, l[r].y - lse, l[r].z - lse, l[r].w - lse);
        }
    }
}

// ================= launch =================

extern "C" void kernel_launch(void* const* d_in, const int* in_sizes, int n_in,
                              void* d_out, int out_size, void* d_ws, size_t ws_size,
                              hipStream_t stream) {
    const float* x   = (const float*)d_in[0];
    const int*   ei  = (const int*)d_in[1];
    const float* W   = (const float*)d_in[2];
    const float* b   = (const float*)d_in[3];
    float*       out = (float*)d_out;

    const int* esrc = ei;
    const int* edst = ei + N_EDGES;

    // workspace layout
    int*   deg     = (int*)d_ws;                       // NPAD
    int*   row_ptr = deg + NPAD;                       // NPAD
    int*   cursor  = row_ptr + NPAD;                   // NPAD
    int*   blksum  = cursor + NPAD;                    // 128
    int*   csr_src = blksum + 128;                     // 600064
    float* dinv    = (float*)(csr_src + 600064);       // NPAD
    unsigned short* u0 = (unsigned short*)(dinv + NPAD);        // 100000*64 bf16
    unsigned short* u1 = u0 + (size_t)N_NODES * USTRIDE;

    const int B = 256;
    const int gE = (N_EDGES + B - 1) / B;              // 2344
    const int gG = (8 * N_NODES + B - 1) / B;          // 3125

    k_zero <<<(NPAD / 4 + B - 1) / B, B, 0, stream>>>((int4*)deg);
    k_count<<<gE, B, 0, stream>>>(edst, deg);
    k_scan1<<<SCAN_NBLK, B, 0, stream>>>(deg, row_ptr, blksum);
    k_scan2<<<SCAN_NBLK, B, 0, stream>>>(deg, row_ptr, cursor, dinv, blksum);
    k_fill <<<gE, B, 0, stream>>>(esrc, edst, cursor, csr_src);

    k_gemm<<<(N_NODES + 63) / 64, B, 0, stream>>>(x, W, dinv, u0);

    k_gather    <<<gG, B, 0, stream>>>(u0, u1, dinv, row_ptr, csr_src);
    k_gather_out<<<gG, B, 0, stream>>>(u1, out, dinv, row_ptr, csr_src, b);
}

// Round 13
// 134.221 us; speedup vs baseline: 1.0825x; 1.0825x over previous
//
#include <hip/hip_runtime.h>

#define N_NODES   100000
#define N_EDGES   600000
#define D_FEAT    128
#define N_CLASSES 40
#define USTRIDE   64                // bf16 elems/row -> 128 B, one cache line

#define NPAD      100352            // N_NODES padded to 1024 multiple
#define SCAN_NBLK (NPAD / 1024)     // 98
#define N_TILES   (N_NODES / 16)    // 6250 exact

typedef __attribute__((ext_vector_type(8))) short bf16x8;
typedef __attribute__((ext_vector_type(4))) float f32x4;

// ---------- bf16 helpers (RTNE) ----------
__device__ __forceinline__ float bf2f(unsigned int h) { return __uint_as_float(h << 16); }
__device__ __forceinline__ unsigned int f2bf(float f) {
    unsigned int u = __float_as_uint(f);
    return (u + 0x7FFFu + ((u >> 16) & 1u)) >> 16;
}
__device__ __forceinline__ float4 up4(uint2 v) {
    return make_float4(bf2f(v.x & 0xFFFFu), bf2f(v.x >> 16),
                       bf2f(v.y & 0xFFFFu), bf2f(v.y >> 16));
}
__device__ __forceinline__ uint2 pk4(float4 f) {
    uint2 r;
    r.x = f2bf(f.x) | (f2bf(f.y) << 16);
    r.y = f2bf(f.z) | (f2bf(f.w) << 16);
    return r;
}

// ================= CSR build =================

__global__ void k_zero(int4* __restrict__ deg4) {
    int i = blockIdx.x * blockDim.x + threadIdx.x;
    if (i < NPAD / 4) deg4[i] = make_int4(0, 0, 0, 0);
}

__global__ void k_count(const int* __restrict__ edst, int* __restrict__ deg) {
    int e = blockIdx.x * blockDim.x + threadIdx.x;
    if (e < N_EDGES) atomicAdd(&deg[edst[e]], 1);
}

__global__ __launch_bounds__(256) void k_scan1(const int* __restrict__ deg,
                                               int* __restrict__ row_ptr,
                                               int* __restrict__ blksum) {
    __shared__ int wsum[4];
    int t = threadIdx.x;
    int lane = t & 63, w = t >> 6;
    int base = blockIdx.x * 1024 + t * 4;
    int4 v = *(const int4*)(deg + base);
    int s0 = v.x, s1 = s0 + v.y, s2 = s1 + v.z, s3 = s2 + v.w;
    int inc = s3;
#pragma unroll
    for (int d = 1; d < 64; d <<= 1) {
        int y = __shfl_up(inc, d, 64);
        if (lane >= d) inc += y;
    }
    if (lane == 63) wsum[w] = inc;
    __syncthreads();
    int woff = 0;
#pragma unroll
    for (int j = 0; j < 3; ++j) woff += (j < w) ? wsum[j] : 0;
    int texcl = woff + inc - s3;
    int4 o;
    o.x = texcl; o.y = texcl + s0; o.z = texcl + s1; o.w = texcl + s2;
    *(int4*)(row_ptr + base) = o;
    if (t == 255) blksum[blockIdx.x] = woff + inc;
}

__global__ __launch_bounds__(256) void k_scan2(const int* __restrict__ deg,
                                               int* __restrict__ row_ptr,
                                               int* __restrict__ cursor,
                                               float* __restrict__ dinv,
                                               const int* __restrict__ blksum) {
    __shared__ int s[SCAN_NBLK];
    int t = threadIdx.x;
    int blk = blockIdx.x;
    if (t < SCAN_NBLK) s[t] = blksum[t];
    __syncthreads();
    int off = 0;
    for (int j = 0; j < blk; ++j) off += s[j];
    int base = blk * 1024 + t * 4;
    int4 v = *(int4*)(row_ptr + base);
    v.x += off; v.y += off; v.z += off; v.w += off;
    *(int4*)(row_ptr + base) = v;
    *(int4*)(cursor + base) = v;
    int4 d = *(const int4*)(deg + base);
    float4 di;
    di.x = rsqrtf((float)(d.x + 1));
    di.y = rsqrtf((float)(d.y + 1));
    di.z = rsqrtf((float)(d.z + 1));
    di.w = rsqrtf((float)(d.w + 1));
    *(float4*)(dinv + base) = di;
}

__global__ void k_fill(const int* __restrict__ esrc, const int* __restrict__ edst,
                       int* __restrict__ cursor, int* __restrict__ csr_src) {
    int e = blockIdx.x * blockDim.x + threadIdx.x;
    if (e < N_EDGES) {
        int d = edst[e];
        int pos = atomicAdd(&cursor[d], 1);
        csr_src[pos] = esrc[e];
    }
}

// ================= u0 = bf16( (x @ W^T) * dinv[node] ) via MFMA =================
// One wave per 16-node tile; 3 class-tiles (40 padded to 48) x 4 K-chunks
// = 12 v_mfma_f32_16x16x32_bf16. Fragment layouts (verified m89):
//   A: row = lane&15, k = (lane>>4)*8 + e  (k-contiguous 8/lane)
//   B: col = lane&15, k = (lane>>4)*8 + e  (mirrors A)
//   D: col = lane&15, row = (lane>>4)*4 + reg
// x and W converted fp32->bf16 in-register (RTNE). Replaces the ~2500
// VALU-instr/thread vector dot (the ~40us floor of rounds 3-12).

__global__ __launch_bounds__(256) void k_gemm(const float* __restrict__ x,
                                              const float* __restrict__ W,
                                              const float* __restrict__ dinv,
                                              unsigned short* __restrict__ y) {
    int t = threadIdx.x;
    int wid = t >> 6;
    int lane = t & 63;
    int tile = blockIdx.x * 4 + wid;
    if (tile >= N_TILES) return;

    int r16 = lane & 15;           // A: node-in-tile / B: class-in-tile
    int g   = lane >> 4;           // k-group (8 elems each)

    // --- B fragments from W (fp32 [40][128]) ---
    bf16x8 bfrag[3][4];
#pragma unroll
    for (int ct = 0; ct < 3; ++ct) {
        int j = ct * 16 + r16;
        bool valid = j < N_CLASSES;
        const float4* wp = (const float4*)(W + (size_t)(valid ? j : 0) * D_FEAT);
#pragma unroll
        for (int kc = 0; kc < 4; ++kc) {
            float4 w0 = wp[kc * 8 + g * 2];
            float4 w1 = wp[kc * 8 + g * 2 + 1];
            if (!valid) { w0 = make_float4(0.f,0.f,0.f,0.f); w1 = make_float4(0.f,0.f,0.f,0.f); }
            union { bf16x8 v; unsigned int u[4]; } tmp;
            tmp.u[0] = f2bf(w0.x) | (f2bf(w0.y) << 16);
            tmp.u[1] = f2bf(w0.z) | (f2bf(w0.w) << 16);
            tmp.u[2] = f2bf(w1.x) | (f2bf(w1.y) << 16);
            tmp.u[3] = f2bf(w1.z) | (f2bf(w1.w) << 16);
            bfrag[ct][kc] = tmp.v;
        }
    }

    // --- A fragments from x, accumulate ---
    int node_r = tile * 16 + r16;
    const float4* xp = (const float4*)(x + (size_t)node_r * D_FEAT);

    f32x4 z = {0.f, 0.f, 0.f, 0.f};
    f32x4 acc0 = z, acc1 = z, acc2 = z;

#pragma unroll
    for (int kc = 0; kc < 4; ++kc) {
        float4 x0 = xp[kc * 8 + g * 2];
        float4 x1 = xp[kc * 8 + g * 2 + 1];
        union { bf16x8 v; unsigned int u[4]; } a;
        a.u[0] = f2bf(x0.x) | (f2bf(x0.y) << 16);
        a.u[1] = f2bf(x0.z) | (f2bf(x0.w) << 16);
        a.u[2] = f2bf(x1.x) | (f2bf(x1.y) << 16);
        a.u[3] = f2bf(x1.z) | (f2bf(x1.w) << 16);
        acc0 = __builtin_amdgcn_mfma_f32_16x16x32_bf16(a.v, bfrag[0][kc], acc0, 0, 0, 0);
        acc1 = __builtin_amdgcn_mfma_f32_16x16x32_bf16(a.v, bfrag[1][kc], acc1, 0, 0, 0);
        acc2 = __builtin_amdgcn_mfma_f32_16x16x32_bf16(a.v, bfrag[2][kc], acc2, 0, 0, 0);
    }

    // --- epilogue: D row=(g*4+reg) node, col=r16 class ---
    int nbase = tile * 16 + g * 4;
#pragma unroll
    for (int r = 0; r < 4; ++r) {
        float di = dinv[nbase + r];
        unsigned short* orow = y + (size_t)(nbase + r) * USTRIDE;
        orow[r16] = (unsigned short)f2bf(acc0[r] * di);                 // classes 0-15
        orow[16 + r16] = (unsigned short)f2bf(acc1[r] * di);            // classes 16-31
        if (r16 < 8) orow[32 + r16] = (unsigned short)f2bf(acc2[r] * di); // classes 32-39
    }
}

// ================= CSR gather on bf16 u (8 threads/node) =================
// u_out[d] = dinv[d]^2 * ( u_in[d] + sum u_in[s] ); rows are ONE 128B line.
// sub = class half (bit0, 5 uint2 = 40B), par = edge phase mod 4 (bits1-2).

__global__ __launch_bounds__(256) void k_gather(const unsigned short* __restrict__ yin,
                                                unsigned short* __restrict__ yout,
                                                const float* __restrict__ dinv,
                                                const int* __restrict__ row_ptr,
                                                const int* __restrict__ csr_src) {
    int t = blockIdx.x * blockDim.x + threadIdx.x;
    int i = t >> 3;
    if (i >= N_NODES) return;
    int sub = t & 1;
    int par = (t >> 1) & 3;
    const uint2* yb = (const uint2*)yin;

    float4 a[5];
    if (par == 0) {
        const uint2* self = yb + (size_t)i * 16 + sub * 5;
#pragma unroll
        for (int r = 0; r < 5; ++r) a[r] = up4(self[r]);
    } else {
#pragma unroll
        for (int r = 0; r < 5; ++r) a[r] = make_float4(0.f, 0.f, 0.f, 0.f);
    }

    int e = row_ptr[i] + par, end = row_ptr[i + 1];
    for (; e < end; e += 4) {
        int s = csr_src[e];
        const uint2* p = yb + (size_t)s * 16 + sub * 5;
        uint2 w[5];
#pragma unroll
        for (int r = 0; r < 5; ++r) w[r] = p[r];
#pragma unroll
        for (int r = 0; r < 5; ++r) {
            float4 v = up4(w[r]);
            a[r].x += v.x; a[r].y += v.y; a[r].z += v.z; a[r].w += v.w;
        }
    }

#pragma unroll
    for (int d = 2; d <= 4; d <<= 1) {
#pragma unroll
        for (int r = 0; r < 5; ++r) {
            a[r].x += __shfl_xor(a[r].x, d); a[r].y += __shfl_xor(a[r].y, d);
            a[r].z += __shfl_xor(a[r].z, d); a[r].w += __shfl_xor(a[r].w, d);
        }
    }

    if (par == 0) {
        float di = dinv[i];
        float s2 = di * di;
        uint2* o = (uint2*)yout + (size_t)i * 16 + sub * 5;
#pragma unroll
        for (int r = 0; r < 5; ++r) {
            o[r] = pk4(make_float4(a[r].x * s2, a[r].y * s2, a[r].z * s2, a[r].w * s2));
        }
    }
}

// final round: logits = dinv*v + b, log_softmax, fp32 out
__global__ __launch_bounds__(256) void k_gather_out(const unsigned short* __restrict__ yin,
                                                    float* __restrict__ out,
                                                    const float* __restrict__ dinv,
                                                    const int* __restrict__ row_ptr,
                                                    const int* __restrict__ csr_src,
                                                    const float* __restrict__ bias) {
    int t = blockIdx.x * blockDim.x + threadIdx.x;
    int i = t >> 3;
    if (i >= N_NODES) return;
    int sub = t & 1;
    int par = (t >> 1) & 3;
    const uint2* yb = (const uint2*)yin;

    float4 a[5];
    if (par == 0) {
        const uint2* self = yb + (size_t)i * 16 + sub * 5;
#pragma unroll
        for (int r = 0; r < 5; ++r) a[r] = up4(self[r]);
    } else {
#pragma unroll
        for (int r = 0; r < 5; ++r) a[r] = make_float4(0.f, 0.f, 0.f, 0.f);
    }

    int e = row_ptr[i] + par, end = row_ptr[i + 1];
    for (; e < end; e += 4) {
        int s = csr_src[e];
        const uint2* p = yb + (size_t)s * 16 + sub * 5;
        uint2 w[5];
#pragma unroll
        for (int r = 0; r < 5; ++r) w[r] = p[r];
#pragma unroll
        for (int r = 0; r < 5; ++r) {
            float4 v = up4(w[r]);
            a[r].x += v.x; a[r].y += v.y; a[r].z += v.z; a[r].w += v.w;
        }
    }

#pragma unroll
    for (int d = 2; d <= 4; d <<= 1) {
#pragma unroll
        for (int r = 0; r < 5; ++r) {
            a[r].x += __shfl_xor(a[r].x, d); a[r].y += __shfl_xor(a[r].y, d);
            a[r].z += __shfl_xor(a[r].z, d); a[r].w += __shfl_xor(a[r].w, d);
        }
    }

    float di = dinv[i];
    const float4* b4 = (const float4*)bias + sub * 5;
    float4 l[5];
    float m = -INFINITY;
#pragma unroll
    for (int r = 0; r < 5; ++r) {
        float4 b = b4[r];
        l[r].x = a[r].x * di + b.x;
        l[r].y = a[r].y * di + b.y;
        l[r].z = a[r].z * di + b.z;
        l[r].w = a[r].w * di + b.w;
        m = fmaxf(m, fmaxf(fmaxf(l[r].x, l[r].y), fmaxf(l[r].z, l[r].w)));
    }
    m = fmaxf(m, __shfl_xor(m, 1));     // combine class halves (bit 0)
    float s = 0.f;
#pragma unroll
    for (int r = 0; r < 5; ++r) {
        s += __expf(l[r].x - m) + __expf(l[r].y - m)
           + __expf(l[r].z - m) + __expf(l[r].w - m);
    }
    s += __shfl_xor(s, 1);
    float lse = __logf(s) + m;

    if (par == 0) {
        float4* o = (float4*)out + (size_t)i * 10 + sub * 5;
#pragma unroll
        for (int r = 0; r < 5; ++r) {
            o[r] = make_float4(l[r].x - lse, l[r].y - lse, l[r].z - lse, l[r].w - lse);
        }
    }
}

// ================= launch =================

extern "C" void kernel_launch(void* const* d_in, const int* in_sizes, int n_in,
                              void* d_out, int out_size, void* d_ws, size_t ws_size,
                              hipStream_t stream) {
    const float* x   = (const float*)d_in[0];
    const int*   ei  = (const int*)d_in[1];
    const float* W   = (const float*)d_in[2];
    const float* b   = (const float*)d_in[3];
    float*       out = (float*)d_out;

    const int* esrc = ei;
    const int* edst = ei + N_EDGES;

    // workspace layout
    int*   deg     = (int*)d_ws;                       // NPAD
    int*   row_ptr = deg + NPAD;                       // NPAD
    int*   cursor  = row_ptr + NPAD;                   // NPAD
    int*   blksum  = cursor + NPAD;                    // 128
    int*   csr_src = blksum + 128;                     // 600064
    float* dinv    = (float*)(csr_src + 600064);       // NPAD
    unsigned short* u0 = (unsigned short*)(dinv + NPAD);        // 100000*64 bf16
    unsigned short* u1 = u0 + (size_t)N_NODES * USTRIDE;

    const int B = 256;
    const int gE = (N_EDGES + B - 1) / B;              // 2344
    const int gG = (8 * N_NODES + B - 1) / B;          // 3125

    k_zero <<<(NPAD / 4 + B - 1) / B, B, 0, stream>>>((int4*)deg);
    k_count<<<gE, B, 0, stream>>>(edst, deg);
    k_scan1<<<SCAN_NBLK, B, 0, stream>>>(deg, row_ptr, blksum);
    k_scan2<<<SCAN_NBLK, B, 0, stream>>>(deg, row_ptr, cursor, dinv, blksum);
    k_fill <<<gE, B, 0, stream>>>(esrc, edst, cursor, csr_src);

    k_gemm<<<(N_TILES + 3) / 4, B, 0, stream>>>(x, W, dinv, u0);

    k_gather    <<<gG, B, 0, stream>>>(u0, u1, dinv, row_ptr, csr_src);
    k_gather_out<<<gG, B, 0, stream>>>(u1, out, dinv, row_ptr, csr_src, b);
}

// Round 14
// 114.903 us; speedup vs baseline: 1.2645x; 1.1681x over previous
//
#include <hip/hip_runtime.h>

#define N_NODES   100000
#define N_EDGES   600000
#define D_FEAT    128
#define N_CLASSES 40
#define USTRIDE   64                // bf16 elems/row -> 128 B, one cache line

#define NPAD      100352            // N_NODES padded to 1024 multiple
#define SCAN_NBLK (NPAD / 1024)     // 98
#define N_TILES   (N_NODES / 16)    // 6250 exact
#define G_GEMM    ((N_TILES + 3) / 4)            // 1563 gemm blocks (4 waves/blk)
#define G_FILL    ((N_EDGES + 255) / 256)        // 2344 fill blocks

typedef __attribute__((ext_vector_type(8))) short bf16x8;
typedef __attribute__((ext_vector_type(4))) float f32x4;

// ---------- bf16 helpers (RTNE) ----------
__device__ __forceinline__ float bf2f(unsigned int h) { return __uint_as_float(h << 16); }
__device__ __forceinline__ unsigned int f2bf(float f) {
    unsigned int u = __float_as_uint(f);
    return (u + 0x7FFFu + ((u >> 16) & 1u)) >> 16;
}
__device__ __forceinline__ float4 up4(uint2 v) {
    return make_float4(bf2f(v.x & 0xFFFFu), bf2f(v.x >> 16),
                       bf2f(v.y & 0xFFFFu), bf2f(v.y >> 16));
}
__device__ __forceinline__ uint2 pk4(float4 f) {
    uint2 r;
    r.x = f2bf(f.x) | (f2bf(f.y) << 16);
    r.y = f2bf(f.z) | (f2bf(f.w) << 16);
    return r;
}

// ================= CSR build =================

__global__ void k_zero(int4* __restrict__ deg4) {
    int i = blockIdx.x * blockDim.x + threadIdx.x;
    if (i < NPAD / 4) deg4[i] = make_int4(0, 0, 0, 0);
}

// count + record per-edge ordinal (makes the fill pass atomic-free)
__global__ void k_count(const int* __restrict__ edst, int* __restrict__ deg,
                        int* __restrict__ ord) {
    int e = blockIdx.x * blockDim.x + threadIdx.x;
    if (e < N_EDGES) ord[e] = atomicAdd(&deg[edst[e]], 1);
}

__global__ __launch_bounds__(256) void k_scan1(const int* __restrict__ deg,
                                               int* __restrict__ row_ptr,
                                               int* __restrict__ blksum) {
    __shared__ int wsum[4];
    int t = threadIdx.x;
    int lane = t & 63, w = t >> 6;
    int base = blockIdx.x * 1024 + t * 4;
    int4 v = *(const int4*)(deg + base);
    int s0 = v.x, s1 = s0 + v.y, s2 = s1 + v.z, s3 = s2 + v.w;
    int inc = s3;
#pragma unroll
    for (int d = 1; d < 64; d <<= 1) {
        int y = __shfl_up(inc, d, 64);
        if (lane >= d) inc += y;
    }
    if (lane == 63) wsum[w] = inc;
    __syncthreads();
    int woff = 0;
#pragma unroll
    for (int j = 0; j < 3; ++j) woff += (j < w) ? wsum[j] : 0;
    int texcl = woff + inc - s3;
    int4 o;
    o.x = texcl; o.y = texcl + s0; o.z = texcl + s1; o.w = texcl + s2;
    *(int4*)(row_ptr + base) = o;
    if (t == 255) blksum[blockIdx.x] = woff + inc;
}

__global__ __launch_bounds__(256) void k_scan2(const int* __restrict__ deg,
                                               int* __restrict__ row_ptr,
                                               float* __restrict__ dinv,
                                               const int* __restrict__ blksum) {
    __shared__ int s[SCAN_NBLK];
    int t = threadIdx.x;
    int blk = blockIdx.x;
    if (t < SCAN_NBLK) s[t] = blksum[t];
    __syncthreads();
    int off = 0;
    for (int j = 0; j < blk; ++j) off += s[j];
    int base = blk * 1024 + t * 4;
    int4 v = *(int4*)(row_ptr + base);
    v.x += off; v.y += off; v.z += off; v.w += off;
    *(int4*)(row_ptr + base) = v;
    int4 d = *(const int4*)(deg + base);
    float4 di;
    di.x = rsqrtf((float)(d.x + 1));
    di.y = rsqrtf((float)(d.y + 1));
    di.z = rsqrtf((float)(d.z + 1));
    di.w = rsqrtf((float)(d.w + 1));
    *(float4*)(dinv + base) = di;
}

// ================= fused: MFMA gemm tiles + CSR fill =================
// Blocks [0, G_GEMM): u0 = bf16( (x @ W^T) * dinv ), one wave per 16-node
// tile, 12 v_mfma_f32_16x16x32_bf16 (layouts verified, round 13 passed).
// Blocks [G_GEMM, G_GEMM+G_FILL): atomic-free CSR fill via precomputed
// ordinals — hides the ~10us fill under the gemm's memory stream.

__global__ __launch_bounds__(256) void k_gemm_fill(const float* __restrict__ x,
                                                   const float* __restrict__ W,
                                                   const float* __restrict__ dinv,
                                                   unsigned short* __restrict__ y,
                                                   const int* __restrict__ esrc,
                                                   const int* __restrict__ edst,
                                                   const int* __restrict__ ord,
                                                   const int* __restrict__ row_ptr,
                                                   int* __restrict__ csr_src) {
    if (blockIdx.x >= G_GEMM) {
        int e = (blockIdx.x - G_GEMM) * 256 + threadIdx.x;
        if (e < N_EDGES) {
            csr_src[row_ptr[edst[e]] + ord[e]] = esrc[e];
        }
        return;
    }

    int t = threadIdx.x;
    int wid = t >> 6;
    int lane = t & 63;
    int tile = blockIdx.x * 4 + wid;
    if (tile >= N_TILES) return;

    int r16 = lane & 15;           // A: node-in-tile / B: class-in-tile
    int g   = lane >> 4;           // k-group (8 elems each)

    // --- B fragments from W (fp32 [40][128]) ---
    bf16x8 bfrag[3][4];
#pragma unroll
    for (int ct = 0; ct < 3; ++ct) {
        int j = ct * 16 + r16;
        bool valid = j < N_CLASSES;
        const float4* wp = (const float4*)(W + (size_t)(valid ? j : 0) * D_FEAT);
#pragma unroll
        for (int kc = 0; kc < 4; ++kc) {
            float4 w0 = wp[kc * 8 + g * 2];
            float4 w1 = wp[kc * 8 + g * 2 + 1];
            if (!valid) { w0 = make_float4(0.f,0.f,0.f,0.f); w1 = make_float4(0.f,0.f,0.f,0.f); }
            union { bf16x8 v; unsigned int u[4]; } tmp;
            tmp.u[0] = f2bf(w0.x) | (f2bf(w0.y) << 16);
            tmp.u[1] = f2bf(w0.z) | (f2bf(w0.w) << 16);
            tmp.u[2] = f2bf(w1.x) | (f2bf(w1.y) << 16);
            tmp.u[3] = f2bf(w1.z) | (f2bf(w1.w) << 16);
            bfrag[ct][kc] = tmp.v;
        }
    }

    // --- A fragments from x, accumulate ---
    int node_r = tile * 16 + r16;
    const float4* xp = (const float4*)(x + (size_t)node_r * D_FEAT);

    f32x4 z = {0.f, 0.f, 0.f, 0.f};
    f32x4 acc0 = z, acc1 = z, acc2 = z;

#pragma unroll
    for (int kc = 0; kc < 4; ++kc) {
        float4 x0 = xp[kc * 8 + g * 2];
        float4 x1 = xp[kc * 8 + g * 2 + 1];
        union { bf16x8 v; unsigned int u[4]; } a;
        a.u[0] = f2bf(x0.x) | (f2bf(x0.y) << 16);
        a.u[1] = f2bf(x0.z) | (f2bf(x0.w) << 16);
        a.u[2] = f2bf(x1.x) | (f2bf(x1.y) << 16);
        a.u[3] = f2bf(x1.z) | (f2bf(x1.w) << 16);
        acc0 = __builtin_amdgcn_mfma_f32_16x16x32_bf16(a.v, bfrag[0][kc], acc0, 0, 0, 0);
        acc1 = __builtin_amdgcn_mfma_f32_16x16x32_bf16(a.v, bfrag[1][kc], acc1, 0, 0, 0);
        acc2 = __builtin_amdgcn_mfma_f32_16x16x32_bf16(a.v, bfrag[2][kc], acc2, 0, 0, 0);
    }

    // --- epilogue: D row=(g*4+reg) node, col=r16 class ---
    int nbase = tile * 16 + g * 4;
#pragma unroll
    for (int r = 0; r < 4; ++r) {
        float di = dinv[nbase + r];
        unsigned short* orow = y + (size_t)(nbase + r) * USTRIDE;
        orow[r16] = (unsigned short)f2bf(acc0[r] * di);                   // classes 0-15
        orow[16 + r16] = (unsigned short)f2bf(acc1[r] * di);              // classes 16-31
        if (r16 < 8) orow[32 + r16] = (unsigned short)f2bf(acc2[r] * di); // classes 32-39
    }
}

// ================= CSR gather on bf16 u (16 threads/node) =================
// u_out[d] = dinv[d]^2 * ( u_in[d] + sum u_in[s] ); rows are ONE 128B line.
// sub = class half (bit0), par = edge phase mod 8 (bits1-3); 25000 waves,
// avg 0.75 edge-iterations per thread; combine via shfl_xor 2,4,8.

__global__ __launch_bounds__(256) void k_gather(const unsigned short* __restrict__ yin,
                                                unsigned short* __restrict__ yout,
                                                const float* __restrict__ dinv,
                                                const int* __restrict__ row_ptr,
                                                const int* __restrict__ csr_src) {
    int t = blockIdx.x * blockDim.x + threadIdx.x;
    int i = t >> 4;
    if (i >= N_NODES) return;
    int sub = t & 1;
    int par = (t >> 1) & 7;
    const uint2* yb = (const uint2*)yin;

    float4 a[5];
    if (par == 0) {
        const uint2* self = yb + (size_t)i * 16 + sub * 5;
#pragma unroll
        for (int r = 0; r < 5; ++r) a[r] = up4(self[r]);
    } else {
#pragma unroll
        for (int r = 0; r < 5; ++r) a[r] = make_float4(0.f, 0.f, 0.f, 0.f);
    }

    int e = row_ptr[i] + par, end = row_ptr[i + 1];
    for (; e < end; e += 8) {
        int s = csr_src[e];
        const uint2* p = yb + (size_t)s * 16 + sub * 5;
        uint2 w[5];
#pragma unroll
        for (int r = 0; r < 5; ++r) w[r] = p[r];
#pragma unroll
        for (int r = 0; r < 5; ++r) {
            float4 v = up4(w[r]);
            a[r].x += v.x; a[r].y += v.y; a[r].z += v.z; a[r].w += v.w;
        }
    }

#pragma unroll
    for (int d = 2; d <= 8; d <<= 1) {
#pragma unroll
        for (int r = 0; r < 5; ++r) {
            a[r].x += __shfl_xor(a[r].x, d); a[r].y += __shfl_xor(a[r].y, d);
            a[r].z += __shfl_xor(a[r].z, d); a[r].w += __shfl_xor(a[r].w, d);
        }
    }

    if (par == 0) {
        float di = dinv[i];
        float s2 = di * di;
        uint2* o = (uint2*)yout + (size_t)i * 16 + sub * 5;
#pragma unroll
        for (int r = 0; r < 5; ++r) {
            o[r] = pk4(make_float4(a[r].x * s2, a[r].y * s2, a[r].z * s2, a[r].w * s2));
        }
    }
}

// final round: logits = dinv*v + b, log_softmax, fp32 out
__global__ __launch_bounds__(256) void k_gather_out(const unsigned short* __restrict__ yin,
                                                    float* __restrict__ out,
                                                    const float* __restrict__ dinv,
                                                    const int* __restrict__ row_ptr,
                                                    const int* __restrict__ csr_src,
                                                    const float* __restrict__ bias) {
    int t = blockIdx.x * blockDim.x + threadIdx.x;
    int i = t >> 4;
    if (i >= N_NODES) return;
    int sub = t & 1;
    int par = (t >> 1) & 7;
    const uint2* yb = (const uint2*)yin;

    float4 a[5];
    if (par == 0) {
        const uint2* self = yb + (size_t)i * 16 + sub * 5;
#pragma unroll
        for (int r = 0; r < 5; ++r) a[r] = up4(self[r]);
    } else {
#pragma unroll
        for (int r = 0; r < 5; ++r) a[r] = make_float4(0.f, 0.f, 0.f, 0.f);
    }

    int e = row_ptr[i] + par, end = row_ptr[i + 1];
    for (; e < end; e += 8) {
        int s = csr_src[e];
        const uint2* p = yb + (size_t)s * 16 + sub * 5;
        uint2 w[5];
#pragma unroll
        for (int r = 0; r < 5; ++r) w[r] = p[r];
#pragma unroll
        for (int r = 0; r < 5; ++r) {
            float4 v = up4(w[r]);
            a[r].x += v.x; a[r].y += v.y; a[r].z += v.z; a[r].w += v.w;
        }
    }

#pragma unroll
    for (int d = 2; d <= 8; d <<= 1) {
#pragma unroll
        for (int r = 0; r < 5; ++r) {
            a[r].x += __shfl_xor(a[r].x, d); a[r].y += __shfl_xor(a[r].y, d);
            a[r].z += __shfl_xor(a[r].z, d); a[r].w += __shfl_xor(a[r].w, d);
        }
    }

    float di = dinv[i];
    const float4* b4 = (const float4*)bias + sub * 5;
    float4 l[5];
    float m = -INFINITY;
#pragma unroll
    for (int r = 0; r < 5; ++r) {
        float4 b = b4[r];
        l[r].x = a[r].x * di + b.x;
        l[r].y = a[r].y * di + b.y;
        l[r].z = a[r].z * di + b.z;
        l[r].w = a[r].w * di + b.w;
        m = fmaxf(m, fmaxf(fmaxf(l[r].x, l[r].y), fmaxf(l[r].z, l[r].w)));
    }
    m = fmaxf(m, __shfl_xor(m, 1));     // combine class halves (bit 0)
    float s = 0.f;
#pragma unroll
    for (int r = 0; r < 5; ++r) {
        s += __expf(l[r].x - m) + __expf(l[r].y - m)
           + __expf(l[r].z - m) + __expf(l[r].w - m);
    }
    s += __shfl_xor(s, 1);
    float lse = __logf(s) + m;

    if (par == 0) {
        float4* o = (float4*)out + (size_t)i * 10 + sub * 5;
#pragma unroll
        for (int r = 0; r < 5; ++r) {
            o[r] = make_float4(l[r].x - lse, l[r].y - lse, l[r].z - lse, l[r].w - lse);
        }
    }
}

// ================= launch =================

extern "C" void kernel_launch(void* const* d_in, const int* in_sizes, int n_in,
                              void* d_out, int out_size, void* d_ws, size_t ws_size,
                              hipStream_t stream) {
    const float* x   = (const float*)d_in[0];
    const int*   ei  = (const int*)d_in[1];
    const float* W   = (const float*)d_in[2];
    const float* b   = (const float*)d_in[3];
    float*       out = (float*)d_out;

    const int* esrc = ei;
    const int* edst = ei + N_EDGES;

    // workspace layout
    int*   deg     = (int*)d_ws;                       // NPAD
    int*   row_ptr = deg + NPAD;                       // NPAD
    int*   blksum  = row_ptr + NPAD;                   // 128
    int*   ord     = blksum + 128;                     // 600064
    int*   csr_src = ord + 600064;                     // 600064
    float* dinv    = (float*)(csr_src + 600064);       // NPAD
    unsigned short* u0 = (unsigned short*)(dinv + NPAD);        // 100000*64 bf16
    unsigned short* u1 = u0 + (size_t)N_NODES * USTRIDE;

    const int B = 256;
    const int gE = G_FILL;                             // 2344
    const int gG = (16 * N_NODES + B - 1) / B;         // 6250 (16 threads/node)

    k_zero <<<(NPAD / 4 + B - 1) / B, B, 0, stream>>>((int4*)deg);
    k_count<<<gE, B, 0, stream>>>(edst, deg, ord);
    k_scan1<<<SCAN_NBLK, B, 0, stream>>>(deg, row_ptr, blksum);
    k_scan2<<<SCAN_NBLK, B, 0, stream>>>(deg, row_ptr, dinv, blksum);

    k_gemm_fill<<<G_GEMM + G_FILL, B, 0, stream>>>(x, W, dinv, u0,
                                                   esrc, edst, ord, row_ptr, csr_src);

    k_gather    <<<gG, B, 0, stream>>>(u0, u1, dinv, row_ptr, csr_src);
    k_gather_out<<<gG, B, 0, stream>>>(u1, out, dinv, row_ptr, csr_src, b);
}

// Round 15
// 103.152 us; speedup vs baseline: 1.4086x; 1.1139x over previous
//
#include <hip/hip_runtime.h>

#define N_NODES   100000
#define N_EDGES   600000
#define D_FEAT    128
#define N_CLASSES 40
#define USTRIDE   64                // bf16 elems/row -> 128 B, one cache line

#define NPAD      100352            // N_NODES padded to 1024 multiple
#define SCAN_NBLK (NPAD / 1024)     // 98
#define N_TILES   (N_NODES / 16)    // 6250 exact
#define G_GEMM    ((N_TILES + 3) / 4)            // 1563 gemm blocks (4 waves/blk)
#define G_FILL    ((N_EDGES + 255) / 256)        // 2344 fill blocks
#define G_ZERO    (NPAD / 4 / 256 + 1)           // 98 zero blocks (+1 below)

typedef __attribute__((ext_vector_type(8))) short bf16x8;
typedef __attribute__((ext_vector_type(4))) float f32x4;

// ---------- bf16 helpers (RTNE) ----------
__device__ __forceinline__ float bf2f(unsigned int h) { return __uint_as_float(h << 16); }
__device__ __forceinline__ unsigned int f2bf(float f) {
    unsigned int u = __float_as_uint(f);
    return (u + 0x7FFFu + ((u >> 16) & 1u)) >> 16;
}
__device__ __forceinline__ float4 up4(uint2 v) {
    return make_float4(bf2f(v.x & 0xFFFFu), bf2f(v.x >> 16),
                       bf2f(v.y & 0xFFFFu), bf2f(v.y >> 16));
}
__device__ __forceinline__ uint2 pk4(float4 f) {
    uint2 r;
    r.x = f2bf(f.x) | (f2bf(f.y) << 16);
    r.y = f2bf(f.z) | (f2bf(f.w) << 16);
    return r;
}

// ================= zero deg + precompute W MFMA fragments =================
// Blocks [0,98): zero deg. Block 98: convert W (fp32 [40][128]) into
// fragment-ordered bf16: wfrag[(ct*4+kc)*64 + lane] = 8 elems of row
// j=ct*16+(lane&15), k = kc*32 + (lane>>4)*8 + 0..7 (zero for j>=40).
// Gemm waves then fetch B-frags as 12 coalesced L1-hot b128 loads instead
// of 24 scattered loads + ~300 VALU of conversion PER WAVE.

__global__ void k_zero_wconv(int4* __restrict__ deg4, const float* __restrict__ W,
                             uint4* __restrict__ wfrag) {
    int t = threadIdx.x;
    if (blockIdx.x < G_ZERO - 1) {
        int i = blockIdx.x * 256 + t;
        if (i < NPAD / 4) deg4[i] = make_int4(0, 0, 0, 0);
        return;
    }
    // 768 fragments, 256 threads -> 3 each
    for (int idx = t; idx < 768; idx += 256) {
        int lane = idx & 63;
        int kc   = (idx >> 6) & 3;
        int ct   = idx >> 8;
        int r16  = lane & 15;
        int g    = lane >> 4;
        int j    = ct * 16 + r16;
        uint4 o = make_uint4(0u, 0u, 0u, 0u);
        if (j < N_CLASSES) {
            const float* wr = W + (size_t)j * D_FEAT + kc * 32 + g * 8;
            float4 w0 = *(const float4*)wr;
            float4 w1 = *(const float4*)(wr + 4);
            o.x = f2bf(w0.x) | (f2bf(w0.y) << 16);
            o.y = f2bf(w0.z) | (f2bf(w0.w) << 16);
            o.z = f2bf(w1.x) | (f2bf(w1.y) << 16);
            o.w = f2bf(w1.z) | (f2bf(w1.w) << 16);
        }
        wfrag[idx] = o;
    }
}

// count + record per-edge ordinal (makes the fill pass atomic-free)
__global__ void k_count(const int* __restrict__ edst, int* __restrict__ deg,
                        int* __restrict__ ord) {
    int e = blockIdx.x * blockDim.x + threadIdx.x;
    if (e < N_EDGES) ord[e] = atomicAdd(&deg[edst[e]], 1);
}

__global__ __launch_bounds__(256) void k_scan1(const int* __restrict__ deg,
                                               int* __restrict__ row_ptr,
                                               int* __restrict__ blksum) {
    __shared__ int wsum[4];
    int t = threadIdx.x;
    int lane = t & 63, w = t >> 6;
    int base = blockIdx.x * 1024 + t * 4;
    int4 v = *(const int4*)(deg + base);
    int s0 = v.x, s1 = s0 + v.y, s2 = s1 + v.z, s3 = s2 + v.w;
    int inc = s3;
#pragma unroll
    for (int d = 1; d < 64; d <<= 1) {
        int y = __shfl_up(inc, d, 64);
        if (lane >= d) inc += y;
    }
    if (lane == 63) wsum[w] = inc;
    __syncthreads();
    int woff = 0;
#pragma unroll
    for (int j = 0; j < 3; ++j) woff += (j < w) ? wsum[j] : 0;
    int texcl = woff + inc - s3;
    int4 o;
    o.x = texcl; o.y = texcl + s0; o.z = texcl + s1; o.w = texcl + s2;
    *(int4*)(row_ptr + base) = o;
    if (t == 255) blksum[blockIdx.x] = woff + inc;
}

__global__ __launch_bounds__(256) void k_scan2(const int* __restrict__ deg,
                                               int* __restrict__ row_ptr,
                                               float* __restrict__ dinv,
                                               const int* __restrict__ blksum) {
    __shared__ int s[SCAN_NBLK];
    int t = threadIdx.x;
    int blk = blockIdx.x;
    if (t < SCAN_NBLK) s[t] = blksum[t];
    __syncthreads();
    int off = 0;
    for (int j = 0; j < blk; ++j) off += s[j];
    int base = blk * 1024 + t * 4;
    int4 v = *(int4*)(row_ptr + base);
    v.x += off; v.y += off; v.z += off; v.w += off;
    *(int4*)(row_ptr + base) = v;
    int4 d = *(const int4*)(deg + base);
    float4 di;
    di.x = rsqrtf((float)(d.x + 1));
    di.y = rsqrtf((float)(d.y + 1));
    di.z = rsqrtf((float)(d.z + 1));
    di.w = rsqrtf((float)(d.w + 1));
    *(float4*)(dinv + base) = di;
}

// ================= fused: MFMA gemm tiles + CSR fill =================

__global__ __launch_bounds__(256) void k_gemm_fill(const float* __restrict__ x,
                                                   const uint4* __restrict__ wfrag,
                                                   const float* __restrict__ dinv,
                                                   unsigned short* __restrict__ y,
                                                   const int* __restrict__ esrc,
                                                   const int* __restrict__ edst,
                                                   const int* __restrict__ ord,
                                                   const int* __restrict__ row_ptr,
                                                   int* __restrict__ csr_src) {
    if (blockIdx.x >= G_GEMM) {
        int e = (blockIdx.x - G_GEMM) * 256 + threadIdx.x;
        if (e < N_EDGES) {
            csr_src[row_ptr[edst[e]] + ord[e]] = esrc[e];
        }
        return;
    }

    int t = threadIdx.x;
    int wid = t >> 6;
    int lane = t & 63;
    int tile = blockIdx.x * 4 + wid;
    if (tile >= N_TILES) return;

    int r16 = lane & 15;           // A: node-in-tile
    int g   = lane >> 4;           // k-group (8 elems each)

    // --- B fragments: precomputed, 12 coalesced L1-hot b128 loads ---
    bf16x8 bfrag[3][4];
#pragma unroll
    for (int ct = 0; ct < 3; ++ct) {
#pragma unroll
        for (int kc = 0; kc < 4; ++kc) {
            union { uint4 u4; bf16x8 v; } tmp;
            tmp.u4 = wfrag[(ct * 4 + kc) * 64 + lane];
            bfrag[ct][kc] = tmp.v;
        }
    }

    // --- A fragments from x, accumulate ---
    int node_r = tile * 16 + r16;
    const float4* xp = (const float4*)(x + (size_t)node_r * D_FEAT);

    f32x4 z = {0.f, 0.f, 0.f, 0.f};
    f32x4 acc0 = z, acc1 = z, acc2 = z;

#pragma unroll
    for (int kc = 0; kc < 4; ++kc) {
        float4 x0 = xp[kc * 8 + g * 2];
        float4 x1 = xp[kc * 8 + g * 2 + 1];
        union { bf16x8 v; unsigned int u[4]; } a;
        a.u[0] = f2bf(x0.x) | (f2bf(x0.y) << 16);
        a.u[1] = f2bf(x0.z) | (f2bf(x0.w) << 16);
        a.u[2] = f2bf(x1.x) | (f2bf(x1.y) << 16);
        a.u[3] = f2bf(x1.z) | (f2bf(x1.w) << 16);
        acc0 = __builtin_amdgcn_mfma_f32_16x16x32_bf16(a.v, bfrag[0][kc], acc0, 0, 0, 0);
        acc1 = __builtin_amdgcn_mfma_f32_16x16x32_bf16(a.v, bfrag[1][kc], acc1, 0, 0, 0);
        acc2 = __builtin_amdgcn_mfma_f32_16x16x32_bf16(a.v, bfrag[2][kc], acc2, 0, 0, 0);
    }

    // --- epilogue: D row=(g*4+reg) node, col=r16 class ---
    int nbase = tile * 16 + g * 4;
#pragma unroll
    for (int r = 0; r < 4; ++r) {
        float di = dinv[nbase + r];
        unsigned short* orow = y + (size_t)(nbase + r) * USTRIDE;
        orow[r16] = (unsigned short)f2bf(acc0[r] * di);                   // classes 0-15
        orow[16 + r16] = (unsigned short)f2bf(acc1[r] * di);              // classes 16-31
        if (r16 < 8) orow[32 + r16] = (unsigned short)f2bf(acc2[r] * di); // classes 32-39
    }
}

// ================= CSR gather on bf16 u (16 threads/node) =================

__global__ __launch_bounds__(256) void k_gather(const unsigned short* __restrict__ yin,
                                                unsigned short* __restrict__ yout,
                                                const float* __restrict__ dinv,
                                                const int* __restrict__ row_ptr,
                                                const int* __restrict__ csr_src) {
    int t = blockIdx.x * blockDim.x + threadIdx.x;
    int i = t >> 4;
    if (i >= N_NODES) return;
    int sub = t & 1;
    int par = (t >> 1) & 7;
    const uint2* yb = (const uint2*)yin;

    float4 a[5];
    if (par == 0) {
        const uint2* self = yb + (size_t)i * 16 + sub * 5;
#pragma unroll
        for (int r = 0; r < 5; ++r) a[r] = up4(self[r]);
    } else {
#pragma unroll
        for (int r = 0; r < 5; ++r) a[r] = make_float4(0.f, 0.f, 0.f, 0.f);
    }

    int e = row_ptr[i] + par, end = row_ptr[i + 1];
    for (; e < end; e += 8) {
        int s = csr_src[e];
        const uint2* p = yb + (size_t)s * 16 + sub * 5;
        uint2 w[5];
#pragma unroll
        for (int r = 0; r < 5; ++r) w[r] = p[r];
#pragma unroll
        for (int r = 0; r < 5; ++r) {
            float4 v = up4(w[r]);
            a[r].x += v.x; a[r].y += v.y; a[r].z += v.z; a[r].w += v.w;
        }
    }

#pragma unroll
    for (int d = 2; d <= 8; d <<= 1) {
#pragma unroll
        for (int r = 0; r < 5; ++r) {
            a[r].x += __shfl_xor(a[r].x, d); a[r].y += __shfl_xor(a[r].y, d);
            a[r].z += __shfl_xor(a[r].z, d); a[r].w += __shfl_xor(a[r].w, d);
        }
    }

    if (par == 0) {
        float di = dinv[i];
        float s2 = di * di;
        uint2* o = (uint2*)yout + (size_t)i * 16 + sub * 5;
#pragma unroll
        for (int r = 0; r < 5; ++r) {
            o[r] = pk4(make_float4(a[r].x * s2, a[r].y * s2, a[r].z * s2, a[r].w * s2));
        }
    }
}

// final round: logits = dinv*v + b, log_softmax, fp32 out
__global__ __launch_bounds__(256) void k_gather_out(const unsigned short* __restrict__ yin,
                                                    float* __restrict__ out,
                                                    const float* __restrict__ dinv,
                                                    const int* __restrict__ row_ptr,
                                                    const int* __restrict__ csr_src,
                                                    const float* __restrict__ bias) {
    int t = blockIdx.x * blockDim.x + threadIdx.x;
    int i = t >> 4;
    if (i >= N_NODES) return;
    int sub = t & 1;
    int par = (t >> 1) & 7;
    const uint2* yb = (const uint2*)yin;

    float4 a[5];
    if (par == 0) {
        const uint2* self = yb + (size_t)i * 16 + sub * 5;
#pragma unroll
        for (int r = 0; r < 5; ++r) a[r] = up4(self[r]);
    } else {
#pragma unroll
        for (int r = 0; r < 5; ++r) a[r] = make_float4(0.f, 0.f, 0.f, 0.f);
    }

    int e = row_ptr[i] + par, end = row_ptr[i + 1];
    for (; e < end; e += 8) {
        int s = csr_src[e];
        const uint2* p = yb + (size_t)s * 16 + sub * 5;
        uint2 w[5];
#pragma unroll
        for (int r = 0; r < 5; ++r) w[r] = p[r];
#pragma unroll
        for (int r = 0; r < 5; ++r) {
            float4 v = up4(w[r]);
            a[r].x += v.x; a[r].y += v.y; a[r].z += v.z; a[r].w += v.w;
        }
    }

#pragma unroll
    for (int d = 2; d <= 8; d <<= 1) {
#pragma unroll
        for (int r = 0; r < 5; ++r) {
            a[r].x += __shfl_xor(a[r].x, d); a[r].y += __shfl_xor(a[r].y, d);
            a[r].z += __shfl_xor(a[r].z, d); a[r].w += __shfl_xor(a[r].w, d);
        }
    }

    float di = dinv[i];
    const float4* b4 = (const float4*)bias + sub * 5;
    float4 l[5];
    float m = -INFINITY;
#pragma unroll
    for (int r = 0; r < 5; ++r) {
        float4 b = b4[r];
        l[r].x = a[r].x * di + b.x;
        l[r].y = a[r].y * di + b.y;
        l[r].z = a[r].z * di + b.z;
        l[r].w = a[r].w * di + b.w;
        m = fmaxf(m, fmaxf(fmaxf(l[r].x, l[r].y), fmaxf(l[r].z, l[r].w)));
    }
    m = fmaxf(m, __shfl_xor(m, 1));     // combine class halves (bit 0)
    float s = 0.f;
#pragma unroll
    for (int r = 0; r < 5; ++r) {
        s += __expf(l[r].x - m) + __expf(l[r].y - m)
           + __expf(l[r].z - m) + __expf(l[r].w - m);
    }
    s += __shfl_xor(s, 1);
    float lse = __logf(s) + m;

    if (par == 0) {
        float4* o = (float4*)out + (size_t)i * 10 + sub * 5;
#pragma unroll
        for (int r = 0; r < 5; ++r) {
            o[r] = make_float4(l[r].x - lse, l[r].y - lse, l[r].z - lse, l[r].w - lse);
        }
    }
}

// ================= launch =================

extern "C" void kernel_launch(void* const* d_in, const int* in_sizes, int n_in,
                              void* d_out, int out_size, void* d_ws, size_t ws_size,
                              hipStream_t stream) {
    const float* x   = (const float*)d_in[0];
    const int*   ei  = (const int*)d_in[1];
    const float* W   = (const float*)d_in[2];
    const float* b   = (const float*)d_in[3];
    float*       out = (float*)d_out;

    const int* esrc = ei;
    const int* edst = ei + N_EDGES;

    // workspace layout
    int*   deg     = (int*)d_ws;                       // NPAD
    int*   row_ptr = deg + NPAD;                       // NPAD
    int*   blksum  = row_ptr + NPAD;                   // 128
    int*   ord     = blksum + 128;                     // 600064
    int*   csr_src = ord + 600064;                     // 600064
    uint4* wfrag   = (uint4*)(csr_src + 600064);       // 768 uint4 (3072 ints)
    float* dinv    = (float*)(csr_src + 600064 + 3072);// NPAD
    unsigned short* u0 = (unsigned short*)(dinv + NPAD);        // 100000*64 bf16
    unsigned short* u1 = u0 + (size_t)N_NODES * USTRIDE;

    const int B = 256;
    const int gE = G_FILL;                             // 2344
    const int gG = (16 * N_NODES + B - 1) / B;         // 6250 (16 threads/node)

    k_zero_wconv<<<G_ZERO, B, 0, stream>>>((int4*)deg, W, wfrag);
    k_count<<<gE, B, 0, stream>>>(edst, deg, ord);
    k_scan1<<<SCAN_NBLK, B, 0, stream>>>(deg, row_ptr, blksum);
    k_scan2<<<SCAN_NBLK, B, 0, stream>>>(deg, row_ptr, dinv, blksum);

    k_gemm_fill<<<G_GEMM + G_FILL, B, 0, stream>>>(x, wfrag, dinv, u0,
                                                   esrc, edst, ord, row_ptr, csr_src);

    k_gather    <<<gG, B, 0, stream>>>(u0, u1, dinv, row_ptr, csr_src);
    k_gather_out<<<gG, B, 0, stream>>>(u1, out, dinv, row_ptr, csr_src, b);
}